// Round 9
// baseline (211.007 us; speedup 1.0000x reference)
//
#include <hip/hip_runtime.h>
#include <stdint.h>
#include <stddef.h>

// ---------------------------------------------------------------------------
// VQ-VAE quantizer, MI355X.  dist(n,k) = ||x||^2 + ||w_k||^2 - 2 x.w_k.
// f16 GEMM (KD=128), fragment-linear A/B.
// Refine (R4-proven): per-row threshold T = d1~ + 2E over 64 col-groups of
// 128 codes; group top-1s within T are candidates; any group top-2 within T
// -> exact full rescan.  Exact compares via u64 atomicMin keys.
// R12: index-embedded pure min/max top-2 network in the gemm epilogue.
// R16: fragments staged via global_load_lds, shared by waves.
// R17/R18: pc1 gone (idx in pd1 mantissa); exact wnmax via wnmax128;
// refine reads xT/xnorm.  R19: 16 KB half-group dbuf (32 KB LDS);
// parallel fill restored.
// R20 (this round): R8 showed occupancy 35->56% with dur FLAT -> gemm is
// LDS-read-pipe bound (8192 ds_read_b128/CU x 12cyc ~ 41 us), not latency
// bound.  (a) DUAL-ROW waves: each wave owns two 16-row tiles (bxA/bxB);
// one ds_read feeds TWO MFMAs -> LDS reads halve (~20 us floor).  Works
// now (vs R4's fail) because fragments come from the staged LDS buffer;
// VGPR ~100 -> 4 waves/SIMD which R8 proved is enough.  Grid (8,64).
// (b) pd transposed to [row][(d1,d2)x64] float2: gemm stores one float2;
// classify = 1 thread/row, 512 B contiguous reads, no shfl merge.
// ---------------------------------------------------------------------------

#define N_ROWS   16384      // B*H*W = 16*32*32
#define K_CODES  8192
#define C_DIM    128

typedef _Float16 f16x8 __attribute__((ext_vector_type(8)));
typedef float    f32x4 __attribute__((ext_vector_type(4)));

// ---------------- fused prep: blocks [0,256) pack x (+fp32 xT), [256,384) w
// Fragment-linear layout: half P[tile16 T=i>>4][kchunk C=c>>5][lane][8]
//   lane = (i&15) + 16*((c&31)>>3), elem j = c&7  (valid as MFMA A or B frag)
__global__ __launch_bounds__(256) void prep(const float* __restrict__ enc,
                                            const float* __restrict__ w,
                                            _Float16* __restrict__ Ap,
                                            _Float16* __restrict__ Bp,
                                            float* __restrict__ xT,
                                            float* __restrict__ xnorm,
                                            float* __restrict__ wnorm,
                                            float* __restrict__ wnmax128) {
  __shared__ float t[128][65];
  const int tid = threadIdx.x;
  if (blockIdx.x < 256) {                        // ---- x path
    const int b = blockIdx.x >> 4;
    const int hw0 = (blockIdx.x & 15) << 6;
    #pragma unroll
    for (int i = 0; i < 32; ++i) {
      int idx = i * 256 + tid;
      int c = idx >> 6, hwl = idx & 63;
      t[c][hwl] = enc[((size_t)(b * 128 + c) << 10) + hw0 + hwl];
    }
    __syncthreads();
    const int r = tid >> 2, sub = tid & 3;       // row-in-block, k-chunk
    const int n = (b << 10) + hw0 + r;
    const int R = n >> 4, m = n & 15;
    float s = 0.f;
    #pragma unroll
    for (int q = 0; q < 4; ++q) {
      f16x8 hv;
      float vv[8];
      #pragma unroll
      for (int e = 0; e < 8; ++e) {
        float v = t[sub * 32 + q * 8 + e][r];
        vv[e] = v;
        s += v * v;
        hv[e] = (_Float16)v;
      }
      *(f16x8*)(Ap + ((size_t)(R * 4 + sub) * 64 + (m + 16 * q)) * 8) = hv;
      *(float4*)(xT + (size_t)n * 128 + sub * 32 + q * 8) =
          (float4){vv[0], vv[1], vv[2], vv[3]};
      *(float4*)(xT + (size_t)n * 128 + sub * 32 + q * 8 + 4) =
          (float4){vv[4], vv[5], vv[6], vv[7]};
    }
    s += __shfl_xor(s, 1);
    s += __shfl_xor(s, 2);
    if (sub == 0) xnorm[n] = s;
  } else {                                       // ---- w path
    __shared__ float wred[4];
    const int kk = (blockIdx.x - 256) * 64 + (tid >> 2), sub = tid & 3;
    const int R = kk >> 4, m = kk & 15;
    const float* base = w + (size_t)kk * C_DIM + sub * 32;
    float s = 0.f;
    #pragma unroll
    for (int q = 0; q < 4; ++q) {
      f16x8 hv;
      float4 va = *(const float4*)(base + q * 8);
      float4 vb = *(const float4*)(base + q * 8 + 4);
      float vv[8] = {va.x, va.y, va.z, va.w, vb.x, vb.y, vb.z, vb.w};
      #pragma unroll
      for (int e = 0; e < 8; ++e) { s += vv[e] * vv[e]; hv[e] = (_Float16)vv[e]; }
      *(f16x8*)(Bp + ((size_t)(R * 4 + sub) * 64 + (m + 16 * q)) * 8) = hv;
    }
    s += __shfl_xor(s, 1);                       // after: all 4 lanes of the
    s += __shfl_xor(s, 2);                       //  quad hold norm(kk)
    if (sub == 0) wnorm[kk] = s;
    float wx = s;                                // block max of 64 norms
    #pragma unroll
    for (int st = 1; st <= 32; st <<= 1) wx = fmaxf(wx, __shfl_xor(wx, st));
    if ((tid & 63) == 0) wred[tid >> 6] = wx;
    __syncthreads();
    if (tid == 0)
      wnmax128[blockIdx.x - 256] =
          fmaxf(fmaxf(wred[0], wred[1]), fmaxf(wred[2], wred[3]));
  }
}

// ---------------- main GEMM + per-(row,128col-group) top-2 -----------------
// Grid (8 colsplits, 64 rowblocks), 512 thr = 8 waves.  Each wave owns TWO
// 16-row tiles (32 rows) x 128 codes per group; one staged ds_read feeds 2
// MFMAs (LDS-pipe bound per R8 -> reads halve).  16 KB half-group dbuf.
// mfma(a=codes, b=rows): D col = lane&15 = x-row, D row = 4q+r = code.
// Scan (per row): idx in low mantissa bits (r@[1:0], tj@[4:2], q@[6:5]),
// per-half min/max top-2 network + carry merge + 2-value shfl reduce.
// pdx[row][(d1,d2) x 64 groups] float2, raw values (classify decodes).
__global__ __launch_bounds__(512) void gemm_argmin(
    const _Float16* __restrict__ Ap, const _Float16* __restrict__ Bp,
    const float* __restrict__ wnorm,
    float* __restrict__ pdx,
    unsigned* __restrict__ icount, unsigned* __restrict__ fcount)
{
  __shared__ _Float16 sbuf[2][8192];             // 2 x 16 KB half-group bufs
  const int tid = threadIdx.x;
  const int lane = tid & 63, wave = tid >> 6;    // 8 waves
  const int m = lane & 15, q = lane >> 4;
  const int cs = blockIdx.x;                     // col slice (1024 codes)
  const int TrA = blockIdx.y * 16 + wave * 2;    // wave's two 16-row tiles

  if (cs == 0 && blockIdx.y == 0 && tid == 0) {  // ctrl zero (pre-classify)
    *icount = 0u; *fcount = 0u;
  }

  // stage half-group hgn (4 tiles = 16 KB contiguous) into sbuf[b]
#define STAGE(b, hgn) do {                                                   \
    const size_t bh_ = ((size_t)((cs * 64 + (hgn) * 4) * 4) << 9);           \
    _Pragma("unroll")                                                        \
    for (int r_ = 0; r_ < 2; ++r_) {                                         \
      __builtin_amdgcn_global_load_lds(                                      \
          (const __attribute__((address_space(1))) void*)                    \
              (Bp + bh_ + ((size_t)(r_ * 512 + tid) << 3)),                  \
          (__attribute__((address_space(3))) void*)                          \
              (&sbuf[b][(r_ * 512 + tid) << 3]),                             \
          16, 0, 0);                                                         \
    }                                                                        \
  } while (0)

  f16x8 bxA[4], bxB[4];                          // x-row fragments (invariant)
  #pragma unroll
  for (int kc = 0; kc < 4; ++kc) {
    bxA[kc] = *(const f16x8*)(Ap + (((size_t)TrA * 4 + kc) << 9) + (lane << 3));
    bxB[kc] = *(const f16x8*)(Ap + (((size_t)(TrA + 1) * 4 + kc) << 9) + (lane << 3));
  }
  const int rowA = blockIdx.y * 256 + wave * 32 + m;
  const int rowB = rowA + 16;
  const unsigned q5 = (unsigned)(q << 5);

  STAGE(0, 0);                                   // prologue stage

  float c1A = 0.f, c2A = 0.f, c1B = 0.f, c2B = 0.f;  // group carries
  for (int hg = 0; hg < 16; ++hg) {              // ascending half-groups
    __syncthreads();                             // buf[hg&1] ready (vmcnt
                                                 //  drained by barrier)
    if (hg < 15) STAGE((hg + 1) & 1, hg + 1);    // prefetch next half
    const _Float16* fb = &sbuf[hg & 1][0];
    const int half = hg & 1;
    f32x4 aA[4], aB[4];
    #pragma unroll
    for (int t = 0; t < 4; ++t) {
      aA[t] = (f32x4){0.f, 0.f, 0.f, 0.f};
      aB[t] = (f32x4){0.f, 0.f, 0.f, 0.f};
    }
    #pragma unroll
    for (int kc = 0; kc < 4; ++kc) {
      #pragma unroll
      for (int t = 0; t < 4; ++t) {
        f16x8 a = *(const f16x8*)(fb + ((t * 4 + kc) << 9) + (lane << 3));
        aA[t] = __builtin_amdgcn_mfma_f32_16x16x32_f16(a, bxA[kc], aA[t], 0, 0, 0);
        aB[t] = __builtin_amdgcn_mfma_f32_16x16x32_f16(a, bxB[kc], aB[t], 0, 0, 0);
      }
    }
    // per-tile top-2 of 4 via min/max network, idx embedded in low bits
    float m1A[4], m2A[4], m1B[4], m2B[4];
    #pragma unroll
    for (int t = 0; t < 4; ++t) {
      const int tj = half * 4 + t;               // tile-in-group
      const int cb = (cs * 64 + hg * 4 + t) * 16 + 4 * q;
      float4 wnq = *(const float4*)(wnorm + cb);
      {
        unsigned b0 = __float_as_uint(fmaf(-2.0f, aA[t][0], wnq.x)) & 0xFFFFFF80u;
        unsigned b1 = __float_as_uint(fmaf(-2.0f, aA[t][1], wnq.y)) & 0xFFFFFF80u;
        unsigned b2 = __float_as_uint(fmaf(-2.0f, aA[t][2], wnq.z)) & 0xFFFFFF80u;
        unsigned b3 = __float_as_uint(fmaf(-2.0f, aA[t][3], wnq.w)) & 0xFFFFFF80u;
        float v0 = __uint_as_float(b0);
        float v1 = __uint_as_float(b1 | 1u);
        float v2 = __uint_as_float(b2 | 2u);
        float v3 = __uint_as_float(b3 | 3u);
        float l1 = fminf(v0, v1), h1 = fmaxf(v0, v1);
        float l2 = fminf(v2, v3), h2 = fmaxf(v2, v3);
        float mm1 = fminf(l1, l2);
        float mm2 = fminf(fminf(h1, h2), fmaxf(l1, l2));
        m1A[t] = __uint_as_float(__float_as_uint(mm1) | (unsigned)(tj << 2));
        m2A[t] = mm2;
      }
      {
        unsigned b0 = __float_as_uint(fmaf(-2.0f, aB[t][0], wnq.x)) & 0xFFFFFF80u;
        unsigned b1 = __float_as_uint(fmaf(-2.0f, aB[t][1], wnq.y)) & 0xFFFFFF80u;
        unsigned b2 = __float_as_uint(fmaf(-2.0f, aB[t][2], wnq.z)) & 0xFFFFFF80u;
        unsigned b3 = __float_as_uint(fmaf(-2.0f, aB[t][3], wnq.w)) & 0xFFFFFF80u;
        float v0 = __uint_as_float(b0);
        float v1 = __uint_as_float(b1 | 1u);
        float v2 = __uint_as_float(b2 | 2u);
        float v3 = __uint_as_float(b3 | 3u);
        float l1 = fminf(v0, v1), h1 = fmaxf(v0, v1);
        float l2 = fminf(v2, v3), h2 = fmaxf(v2, v3);
        float mm1 = fminf(l1, l2);
        float mm2 = fminf(fminf(h1, h2), fmaxf(l1, l2));
        m1B[t] = __uint_as_float(__float_as_uint(mm1) | (unsigned)(tj << 2));
        m2B[t] = mm2;
      }
    }
    // tournament 4 -> 1 per row (pure min/max; idx bits ride along)
    m2A[0] = fminf(fminf(m2A[0], m2A[1]), fmaxf(m1A[0], m1A[1]));
    m1A[0] = fminf(m1A[0], m1A[1]);
    m2A[2] = fminf(fminf(m2A[2], m2A[3]), fmaxf(m1A[2], m1A[3]));
    m1A[2] = fminf(m1A[2], m1A[3]);
    m2A[0] = fminf(fminf(m2A[0], m2A[2]), fmaxf(m1A[0], m1A[2]));
    m1A[0] = fminf(m1A[0], m1A[2]);
    m2B[0] = fminf(fminf(m2B[0], m2B[1]), fmaxf(m1B[0], m1B[1]));
    m1B[0] = fminf(m1B[0], m1B[1]);
    m2B[2] = fminf(fminf(m2B[2], m2B[3]), fmaxf(m1B[2], m1B[3]));
    m1B[2] = fminf(m1B[2], m1B[3]);
    m2B[0] = fminf(fminf(m2B[0], m2B[2]), fmaxf(m1B[0], m1B[2]));
    m1B[0] = fminf(m1B[0], m1B[2]);
    if (half == 0) {                             // first half: set carries
      c1A = m1A[0]; c2A = m2A[0];
      c1B = m1B[0]; c2B = m2B[0];
    } else {                                     // second half: merge + emit
      c2A = fminf(fminf(c2A, m2A[0]), fmaxf(c1A, m1A[0]));
      c1A = fminf(c1A, m1A[0]);
      c2B = fminf(fminf(c2B, m2B[0]), fmaxf(c1B, m1B[0]));
      c1B = fminf(c1B, m1B[0]);
      float d1A = __uint_as_float(__float_as_uint(c1A) | q5);
      float d2A = c2A;
      float d1B = __uint_as_float(__float_as_uint(c1B) | q5);
      float d2B = c2B;
      // reduce across q (lanes differing in bits 4,5)
      #pragma unroll
      for (int s = 16; s <= 32; s <<= 1) {
        float o1 = __shfl_xor(d1A, s), o2 = __shfl_xor(d2A, s);
        d2A = fminf(fminf(d2A, o2), fmaxf(d1A, o1));
        d1A = fminf(d1A, o1);
        float p1 = __shfl_xor(d1B, s), p2 = __shfl_xor(d2B, s);
        d2B = fminf(fminf(d2B, p2), fmaxf(d1B, p1));
        d1B = fminf(d1B, p1);
      }
      if (q == 0) {
        const int g = cs * 8 + (hg >> 1);        // group index [0,64)
        *(float2*)(pdx + ((size_t)rowA << 7) + 2 * g) = (float2){d1A, d2A};
        *(float2*)(pdx + ((size_t)rowB << 7) + 2 * g) = (float2){d1B, d2B};
      }
    }
  }
#undef STAGE
}

// ---------------- classify: threshold-collect over 64 groups ---------------
// 1 thread per row; pdx[row][...] is 512 B contiguous (32 float4 reads).
// Decodes candidate codes from pd1's embedded mantissa bits (q@[6:5]
// tj@[4:2] r@[1:0]).  wm = exact max||w||^2 from wnmax128.  Inits keys/cnt.
__global__ __launch_bounds__(256) void classify(
    const float* __restrict__ pdx,
    const float* __restrict__ xnorm, const float* __restrict__ wnmax128,
    int* __restrict__ ids, unsigned* __restrict__ items,
    unsigned* __restrict__ icount, int* __restrict__ fulll,
    unsigned* __restrict__ fcount, unsigned long long* __restrict__ keys,
    unsigned* __restrict__ cnt)
{
  __shared__ float wred[4];
  const int tid = threadIdx.x;
  const int row = blockIdx.x * 256 + tid;        // 64 blocks
  keys[row] = ~0ull;                             // init for refine/resolve
  if (row < K_CODES) cnt[row] = 0u;
  // exact wm: block-reduce the 128 per-prep-block maxima
  float wv = wnmax128[tid & 127];
  #pragma unroll
  for (int st = 1; st <= 32; st <<= 1) wv = fmaxf(wv, __shfl_xor(wv, st));
  if ((tid & 63) == 0) wred[tid >> 6] = wv;
  __syncthreads();
  const float wm = fmaxf(fmaxf(wred[0], wred[1]), fmaxf(wred[2], wred[3]));

  const float* pr = pdx + ((size_t)row << 7);
  float lmin = __builtin_inff();
  #pragma unroll
  for (int j = 0; j < 32; ++j) {                 // (d1,d2) x 2 per float4
    float4 v = *(const float4*)(pr + j * 4);
    lmin = fminf(lmin, fminf(v.x, v.z));
  }
  // eps 5e-4 covers 2x 127ulp(|dd|<=8) mantissa-mask error
  float twoE = 2.0f * (0.0029297f * sqrtf(xnorm[row] * wm) + 5e-4f);
  float T = lmin + twoE;
  bool full = false;
  int nc = 0;
  unsigned cands[6];
  #pragma unroll
  for (int j = 0; j < 32; ++j) {
    float4 v = *(const float4*)(pr + j * 4);
    if (v.y <= T) { full = true; }
    else if (v.x <= T) {
      if (nc < 6) {
        unsigned ui = __float_as_uint(v.x) & 127u;
        unsigned g = (unsigned)(2 * j);
        cands[nc++] = (g << 7) | (((ui >> 2) & 7u) << 4) |
                      ((ui >> 5) << 2) | (ui & 3u);
      } else full = true;
    }
    if (v.w <= T) { full = true; }
    else if (v.z <= T) {
      if (nc < 6) {
        unsigned ui = __float_as_uint(v.z) & 127u;
        unsigned g = (unsigned)(2 * j + 1);
        cands[nc++] = (g << 7) | (((ui >> 2) & 7u) << 4) |
                      ((ui >> 5) << 2) | (ui & 3u);
      } else full = true;
    }
  }
  if (full) {
    unsigned fi = atomicAdd(fcount, 1u);
    fulll[fi] = row;
  } else if (nc >= 2) {
    unsigned base = atomicAdd(icount, (unsigned)nc);
    for (int i2 = 0; i2 < nc; ++i2)
      items[base + i2] = ((unsigned)row << 13) | cands[i2];
  } else {                                       // nc==1: unique group within
    ids[row] = (int)cands[0];                    //  T -> its top-1 is exact
  }
}

// ---------------- fused exact refine: items (phase A) + full (phase B) -----
// x rows come from xT (row-contiguous fp32) + xnorm.  Safe: each row is
// exclusively phase-A or phase-B; xn is a per-row additive constant.
__global__ __launch_bounds__(256) void refine(
    const float* __restrict__ xT, const float* __restrict__ w,
    const float* __restrict__ xnorm, const float* __restrict__ wnorm,
    const unsigned* __restrict__ items, const unsigned* __restrict__ icount,
    const int* __restrict__ fulll, const unsigned* __restrict__ fcount,
    unsigned long long* __restrict__ keys) {
  const int tid = threadIdx.x;
  const int lane = tid & 63, wave = tid >> 6;
  // ---- phase A: candidate items
  const unsigned ic = *icount;
  for (unsigned i = blockIdx.x * 256 + tid; i < ic; i += gridDim.x * 256) {
    unsigned it = items[i];
    int row = (int)(it >> 13), c = (int)(it & 8191u);
    const float* xb = xT + (size_t)row * C_DIM;
    const float* wk = w + (size_t)c * C_DIM;
    float s = 0.f;
    #pragma unroll 8
    for (int c4 = 0; c4 < 32; ++c4) {
      float4 xv = *(const float4*)(xb + c4 * 4);
      float4 wv = *(const float4*)(wk + c4 * 4);
      s = fmaf(xv.x, wv.x, s);
      s = fmaf(xv.y, wv.y, s);
      s = fmaf(xv.z, wv.z, s);
      s = fmaf(xv.w, wv.w, s);
    }
    float d = (xnorm[row] + wnorm[c]) - 2.0f * s;
    unsigned sb = __float_as_uint(d);
    sb = (sb >> 31) ? ~sb : (sb | 0x80000000u);  // sortable float bits
    unsigned long long key = ((unsigned long long)sb << 32) | (unsigned)c;
    atomicMin(&keys[row], key);                  // tie -> lowest code
  }
  // ---- phase B: full rescans, sliced over the codebook
  __shared__ __align__(16) float xs[128];
  __shared__ unsigned long long red[4];
  const unsigned nitems = *fcount * 8;
  for (unsigned item = blockIdx.x; item < nitems; item += gridDim.x) {
    const int row = fulll[item >> 3];
    const int slice = (int)(item & 7u);
    if (tid < 128)                               // stage x row (coalesced)
      xs[tid] = xT[(size_t)row * C_DIM + tid];
    __syncthreads();
    const float xn = xnorm[row];
    const int k0 = slice * 1024 + tid * 4;
    float S[4];
    #pragma unroll
    for (int j = 0; j < 4; ++j) S[j] = 0.f;
    for (int c4 = 0; c4 < 32; ++c4) {
      float4 xv = *(const float4*)(&xs[c4 * 4]);
      #pragma unroll
      for (int j = 0; j < 4; ++j) {
        float4 wv = *(const float4*)(w + (size_t)(k0 + j) * C_DIM + c4 * 4);
        S[j] = fmaf(xv.x, wv.x, S[j]);
        S[j] = fmaf(xv.y, wv.y, S[j]);
        S[j] = fmaf(xv.z, wv.z, S[j]);
        S[j] = fmaf(xv.w, wv.w, S[j]);
      }
    }
    unsigned long long best = ~0ull;
    #pragma unroll
    for (int j = 0; j < 4; ++j) {
      float d = (xn + wnorm[k0 + j]) - 2.0f * S[j];
      unsigned sb = __float_as_uint(d);
      sb = (sb >> 31) ? ~sb : (sb | 0x80000000u);
      unsigned long long key = ((unsigned long long)sb << 32) | (unsigned)(k0 + j);
      best = best < key ? best : key;
    }
    #pragma unroll
    for (int s = 1; s <= 32; s <<= 1) {          // 64-lane u64 butterfly
      unsigned long long ok = __shfl_xor(best, s);
      best = ok < best ? ok : best;
    }
    if (lane == 0) red[wave] = best;
    __syncthreads();
    if (tid == 0) {
      unsigned long long bk = red[0];
      #pragma unroll
      for (int wv = 1; wv < 4; ++wv) bk = red[wv] < bk ? red[wv] : bk;
      atomicMin(&keys[row], bk);
    }
    __syncthreads();                             // xs reused next item
  }
}

// ---------------- resolve final ids + int counts + out_ids -----------------
__global__ void resolve_ids(const unsigned long long* __restrict__ keys,
                            int* __restrict__ ids, unsigned* __restrict__ cnt,
                            float* __restrict__ out_ids) {
  int row = blockIdx.x * 256 + threadIdx.x;
  unsigned long long k = keys[row];
  int id = (k != ~0ull) ? (int)(unsigned)(k & 0xffffffffu) : ids[row];
  ids[row] = id;
  out_ids[row] = (float)id;
  atomicAdd(&cnt[id], 1u);
}

// ---------------- exclusive scan of counts -> offs + cursor (1 block) ------
__global__ __launch_bounds__(256) void scan_offsets(
    const unsigned* __restrict__ cnt,
    unsigned* __restrict__ offs, unsigned* __restrict__ cursor) {
  __shared__ unsigned tot[256];
  const int tid = threadIdx.x;
  unsigned local[32], run = 0;
  #pragma unroll
  for (int i = 0; i < 32; ++i) { local[i] = run; run += cnt[tid * 32 + i]; }
  tot[tid] = run;
  __syncthreads();
  for (int st = 1; st < 256; st <<= 1) {
    unsigned v = (tid >= st) ? tot[tid - st] : 0u;
    __syncthreads();
    tot[tid] += v;
    __syncthreads();
  }
  unsigned excl = (tid == 0) ? 0u : tot[tid - 1];
  #pragma unroll
  for (int i = 0; i < 32; ++i) {
    unsigned o = excl + local[i];
    offs[tid * 32 + i] = o;
    cursor[tid * 32 + i] = o;
  }
}

// ---------------- fill CSR row list (parallel, 64 blocks) ------------------
__global__ void fill_rowlist(const int* __restrict__ ids,
                             unsigned* __restrict__ cursor,
                             int* __restrict__ rowlist) {
  int row = blockIdx.x * 256 + threadIdx.x;
  unsigned slot = atomicAdd(&cursor[ids[row]], 1u);
  rowlist[slot] = row;
}

// ---------------- fused tail: q float4 (blocks<2048) + EMA gather (rest) ---
__global__ __launch_bounds__(256) void qsum_final(
    const float* __restrict__ enc, const float* __restrict__ w,
    const int* __restrict__ ids,
    const unsigned* __restrict__ cnt, const unsigned* __restrict__ offs,
    const int* __restrict__ rowlist, const float* __restrict__ xT,
    float* __restrict__ outq, float* __restrict__ outw) {
  if (blockIdx.x < 2048) {                       // ---- straight-through q
    int e = blockIdx.x * 1024 + threadIdx.x * 4; // linear over enc [B,C,H,W]
    int c = (e >> 10) & 127;
    int b = e >> 17;
    int n = (b << 10) | (e & 1023);              // e..e+3: same b,c
    float4 x = *(const float4*)(enc + e);
    float4 o;
    o.x = x.x + (w[(size_t)ids[n + 0] * C_DIM + c] - x.x);
    o.y = x.y + (w[(size_t)ids[n + 1] * C_DIM + c] - x.y);
    o.z = x.z + (w[(size_t)ids[n + 2] * C_DIM + c] - x.z);
    o.w = x.w + (w[(size_t)ids[n + 3] * C_DIM + c] - x.w);
    *(float4*)(outq + e) = o;
  } else {                                       // ---- EMA gather, wave/code
    const int tid = threadIdx.x;
    const int lane = tid & 63, wave = tid >> 6;
    const int k = (int)(blockIdx.x - 2048) * 4 + wave;
    const unsigned n0 = offs[k], nk = cnt[k];
    float S0a = 0.f, S0b = 0.f, S0c = 0.f, S0d = 0.f;
    float S1a = 0.f, S1b = 0.f, S1c = 0.f, S1d = 0.f;
    unsigned i = 0;
    for (; i + 4 <= nk; i += 4) {                // 4-way ILP partial sums
      int r0 = rowlist[n0 + i],     r1 = rowlist[n0 + i + 1];
      int r2 = rowlist[n0 + i + 2], r3 = rowlist[n0 + i + 3];
      S0a += xT[(size_t)r0 * 128 + lane];      S1a += xT[(size_t)r0 * 128 + lane + 64];
      S0b += xT[(size_t)r1 * 128 + lane];      S1b += xT[(size_t)r1 * 128 + lane + 64];
      S0c += xT[(size_t)r2 * 128 + lane];      S1c += xT[(size_t)r2 * 128 + lane + 64];
      S0d += xT[(size_t)r3 * 128 + lane];      S1d += xT[(size_t)r3 * 128 + lane + 64];
    }
    for (; i < nk; ++i) {
      int r = rowlist[n0 + i];
      S0a += xT[(size_t)r * 128 + lane];
      S1a += xT[(size_t)r * 128 + lane + 64];
    }
    float S0 = (S0a + S0b) + (S0c + S0d);
    float S1 = (S1a + S1b) + (S1c + S1d);
    const float omd = (float)(1.0 - 0.99);
    float cf = (float)nk + 1e-12f;
    outw[(size_t)k * 128 + lane]      = 0.99f * w[(size_t)k * 128 + lane]      + omd * (S0 / cf);
    outw[(size_t)k * 128 + lane + 64] = 0.99f * w[(size_t)k * 128 + lane + 64] + omd * (S1 / cf);
  }
}

// ---------------------------------------------------------------------------
extern "C" void kernel_launch(void* const* d_in, const int* in_sizes, int n_in,
                              void* d_out, int out_size, void* d_ws, size_t ws_size,
                              hipStream_t stream) {
  const float* enc = (const float*)d_in[0];      // [16,128,32,32]
  const float* w   = (const float*)d_in[1];      // [8192,128]
  float* out = (float*)d_out;
  float* out_ids = out;                          // 16384 (ids as float)
  float* out_q   = out + N_ROWS;                 // 2097152
  float* out_w   = out + N_ROWS + N_ROWS * C_DIM;// 1048576

  char* ws = (char*)d_ws;
  _Float16* Ap  = (_Float16*)(ws);                         //  0 .. 4194304
  _Float16* Bp  = (_Float16*)(ws + 4194304);               //  .. 6291456
  float* xnorm  = (float*)(ws + 6291456);                  //  .. 6356992
  float* wnorm  = (float*)(ws + 6356992);                  //  .. 6389760
  float* pdx    = (float*)(ws + 6389760);                  // 8 MB [row][128]
  float* wnmax128 = (float*)(ws + 14778368);               // 512 B
  int* ids      = (int*)(ws + 18972672);                   // 64 KB
  int* fulll    = (int*)(ws + 19038208);                   // 64 KB
  unsigned* items = (unsigned*)(ws + 19103744);            // 1 MB
  unsigned* icount = (unsigned*)(ws + 20152324);           // ctrl
  unsigned* fcount = (unsigned*)(ws + 20152328);
  unsigned* cnt    = (unsigned*)(ws + 20152336);           // 32 KB (int counts)
  unsigned* offs   = (unsigned*)(ws + 20185104);           // 32 KB
  unsigned* cursor = (unsigned*)(ws + 20217872);           // 32 KB
  unsigned long long* keys = (unsigned long long*)(ws + 20250640); // 128 KB
  int* rowlist  = (int*)(ws + 20381712);                   // 64 KB
  float* xT     = (float*)(ws + 20447248);                 // 8 MB .. 28835856
  (void)in_sizes; (void)n_in; (void)out_size; (void)ws_size;

  // no memset node: icount/fcount zeroed in gemm; keys+cnt init in classify;
  // wnmax128 plain-stored by prep (no init needed)

  prep<<<384, 256, 0, stream>>>(enc, w, Ap, Bp, xT, xnorm, wnorm, wnmax128);
  gemm_argmin<<<dim3(8, N_ROWS / 256), 512, 0, stream>>>(
      Ap, Bp, wnorm, pdx, icount, fcount);
  classify<<<N_ROWS / 256, 256, 0, stream>>>(
      pdx, xnorm, wnmax128, ids, items, icount, fulll, fcount, keys, cnt);
  refine<<<2048, 256, 0, stream>>>(xT, w, xnorm, wnorm, items, icount, fulll,
                                   fcount, keys);
  resolve_ids<<<N_ROWS / 256, 256, 0, stream>>>(keys, ids, cnt, out_ids);
  scan_offsets<<<1, 256, 0, stream>>>(cnt, offs, cursor);
  fill_rowlist<<<N_ROWS / 256, 256, 0, stream>>>(ids, cursor, rowlist);
  qsum_final<<<2048 + K_CODES / 4, 256, 0, stream>>>(
      enc, w, ids, cnt, offs, rowlist, xT, out_q, out_w);
}

// Round 10
// 199.169 us; speedup vs baseline: 1.0594x; 1.0594x over previous
//
#include <hip/hip_runtime.h>
#include <stdint.h>
#include <stddef.h>

// ---------------------------------------------------------------------------
// VQ-VAE quantizer, MI355X.  dist(n,k) = ||x||^2 + ||w_k||^2 - 2 x.w_k.
// f16 GEMM (KD=128), fragment-linear A/B.
// Refine (R4-proven): per-row threshold T = d1~ + 2E over 64 col-groups of
// 128 codes; group top-1s within T are candidates; any group top-2 within T
// -> exact full rescan.  Exact compares via u64 atomicMin keys.
// R12: index-embedded pure min/max top-2 network in the gemm epilogue.
// R16: fragments staged via global_load_lds, shared by waves.
// R17/R18: pc1 gone (idx in pd1 mantissa); exact wnmax via wnmax128;
// refine reads xT/xnorm.  R19: 16 KB half-group dbuf (32 KB LDS, 4 blk/CU);
// parallel fill.  R20 (dual-row): REVERTED — 59.4 vs 55.4 us, third flat
// structural variant -> gemm is at its composite floor; stop tuning it.
// R21 (this round): refine phase B batched 8 rows/item.  Old: each
// (row,slice) item streamed 512 KB of codebook -> fcount x 4 MB of L2
// traffic (the hidden ~30-60 us under gemm in top-5).  New: item =
// (8-row batch, slice); 8 x-rows staged in LDS (broadcast), w-slice
// streamed ONCE per 8 rows -> codebook traffic /8.  Numerics BIT-IDENTICAL:
// each (row,code) dot is still one thread's c4-major fmaf chain in the
// same xyzw order; only work assignment moved.  Tail batches pad with
// duplicate rows (atomicMin idempotent).
// ---------------------------------------------------------------------------

#define N_ROWS   16384      // B*H*W = 16*32*32
#define K_CODES  8192
#define C_DIM    128

typedef _Float16 f16x8 __attribute__((ext_vector_type(8)));
typedef float    f32x4 __attribute__((ext_vector_type(4)));

// ---------------- fused prep: blocks [0,256) pack x (+fp32 xT), [256,384) w
// Fragment-linear layout: half P[tile16 T=i>>4][kchunk C=c>>5][lane][8]
//   lane = (i&15) + 16*((c&31)>>3), elem j = c&7  (valid as MFMA A or B frag)
__global__ __launch_bounds__(256) void prep(const float* __restrict__ enc,
                                            const float* __restrict__ w,
                                            _Float16* __restrict__ Ap,
                                            _Float16* __restrict__ Bp,
                                            float* __restrict__ xT,
                                            float* __restrict__ xnorm,
                                            float* __restrict__ wnorm,
                                            float* __restrict__ wnmax128) {
  __shared__ float t[128][65];
  const int tid = threadIdx.x;
  if (blockIdx.x < 256) {                        // ---- x path
    const int b = blockIdx.x >> 4;
    const int hw0 = (blockIdx.x & 15) << 6;
    #pragma unroll
    for (int i = 0; i < 32; ++i) {
      int idx = i * 256 + tid;
      int c = idx >> 6, hwl = idx & 63;
      t[c][hwl] = enc[((size_t)(b * 128 + c) << 10) + hw0 + hwl];
    }
    __syncthreads();
    const int r = tid >> 2, sub = tid & 3;       // row-in-block, k-chunk
    const int n = (b << 10) + hw0 + r;
    const int R = n >> 4, m = n & 15;
    float s = 0.f;
    #pragma unroll
    for (int q = 0; q < 4; ++q) {
      f16x8 hv;
      float vv[8];
      #pragma unroll
      for (int e = 0; e < 8; ++e) {
        float v = t[sub * 32 + q * 8 + e][r];
        vv[e] = v;
        s += v * v;
        hv[e] = (_Float16)v;
      }
      *(f16x8*)(Ap + ((size_t)(R * 4 + sub) * 64 + (m + 16 * q)) * 8) = hv;
      *(float4*)(xT + (size_t)n * 128 + sub * 32 + q * 8) =
          (float4){vv[0], vv[1], vv[2], vv[3]};
      *(float4*)(xT + (size_t)n * 128 + sub * 32 + q * 8 + 4) =
          (float4){vv[4], vv[5], vv[6], vv[7]};
    }
    s += __shfl_xor(s, 1);
    s += __shfl_xor(s, 2);
    if (sub == 0) xnorm[n] = s;
  } else {                                       // ---- w path
    __shared__ float wred[4];
    const int kk = (blockIdx.x - 256) * 64 + (tid >> 2), sub = tid & 3;
    const int R = kk >> 4, m = kk & 15;
    const float* base = w + (size_t)kk * C_DIM + sub * 32;
    float s = 0.f;
    #pragma unroll
    for (int q = 0; q < 4; ++q) {
      f16x8 hv;
      float4 va = *(const float4*)(base + q * 8);
      float4 vb = *(const float4*)(base + q * 8 + 4);
      float vv[8] = {va.x, va.y, va.z, va.w, vb.x, vb.y, vb.z, vb.w};
      #pragma unroll
      for (int e = 0; e < 8; ++e) { s += vv[e] * vv[e]; hv[e] = (_Float16)vv[e]; }
      *(f16x8*)(Bp + ((size_t)(R * 4 + sub) * 64 + (m + 16 * q)) * 8) = hv;
    }
    s += __shfl_xor(s, 1);                       // after: all 4 lanes of the
    s += __shfl_xor(s, 2);                       //  quad hold norm(kk)
    if (sub == 0) wnorm[kk] = s;
    float wx = s;                                // block max of 64 norms
    #pragma unroll
    for (int st = 1; st <= 32; st <<= 1) wx = fmaxf(wx, __shfl_xor(wx, st));
    if ((tid & 63) == 0) wred[tid >> 6] = wx;
    __syncthreads();
    if (tid == 0)
      wnmax128[blockIdx.x - 256] =
          fmaxf(fmaxf(wred[0], wred[1]), fmaxf(wred[2], wred[3]));
  }
}

// ---------------- main GEMM + per-(row,128col-group) top-2 -----------------
// Grid (8 colsplits, 128 rowblocks), 512 thr = 8 waves.  Wave tile: 16 rows
// (B operand) x 128 codes per group, processed as 16 HALF-groups of 4 code
// tiles (16 KB each), staged via global_load_lds into a 2x16 KB dbuf
// (32 KB LDS -> 4 blocks/CU).  mfma(a=codes, b=rows): D col = lane&15 =
// x-row, D row = 4q+r = code.  Scan: idx embedded in low mantissa bits
// (r@[1:0], tj@[4:2], q@[6:5]), per-half min/max top-2 network + carry
// merge across halves + 2-value shfl reduce.  pd1/pd2 stored RAW (idx bits
// in pd1 mantissa; classify decodes).  Near-ties (<2E) -> exact path.
__global__ __launch_bounds__(512) void gemm_argmin(
    const _Float16* __restrict__ Ap, const _Float16* __restrict__ Bp,
    const float* __restrict__ wnorm,
    float* __restrict__ pd1, float* __restrict__ pd2,
    unsigned* __restrict__ icount, unsigned* __restrict__ fcount)
{
  __shared__ _Float16 sbuf[2][8192];             // 2 x 16 KB half-group bufs
  const int tid = threadIdx.x;
  const int lane = tid & 63, wave = tid >> 6;    // 8 waves
  const int m = lane & 15, q = lane >> 4;
  const int cs = blockIdx.x;                     // col slice (1024 codes)
  const int row0 = blockIdx.y * 128;
  const int Tr = blockIdx.y * 8 + wave;          // wave's 16-row tile

  if (cs == 0 && blockIdx.y == 0 && tid == 0) {  // ctrl zero (pre-classify)
    *icount = 0u; *fcount = 0u;
  }

  // stage half-group hgn (4 tiles = 16 KB contiguous) into sbuf[b]
#define STAGE(b, hgn) do {                                                   \
    const size_t bh_ = ((size_t)((cs * 64 + (hgn) * 4) * 4) << 9);           \
    _Pragma("unroll")                                                        \
    for (int r_ = 0; r_ < 2; ++r_) {                                         \
      __builtin_amdgcn_global_load_lds(                                      \
          (const __attribute__((address_space(1))) void*)                    \
              (Bp + bh_ + ((size_t)(r_ * 512 + tid) << 3)),                  \
          (__attribute__((address_space(3))) void*)                          \
              (&sbuf[b][(r_ * 512 + tid) << 3]),                             \
          16, 0, 0);                                                         \
    }                                                                        \
  } while (0)

  f16x8 bx[4];                                   // x-row fragments (invariant)
  #pragma unroll
  for (int kc = 0; kc < 4; ++kc)
    bx[kc] = *(const f16x8*)(Ap + (((size_t)Tr * 4 + kc) << 9) + (lane << 3));
  const int row = row0 + wave * 16 + m;
  const unsigned q5 = (unsigned)(q << 5);

  STAGE(0, 0);                                   // prologue stage

  float c1 = 0.f, c2 = 0.f;                      // group carry (set at half 0)
  for (int hg = 0; hg < 16; ++hg) {              // ascending half-groups
    __syncthreads();                             // buf[hg&1] ready (vmcnt
                                                 //  drained by barrier)
    if (hg < 15) STAGE((hg + 1) & 1, hg + 1);    // prefetch next half
    const _Float16* fb = &sbuf[hg & 1][0];
    const int half = hg & 1;
    f32x4 acc[4];
    #pragma unroll
    for (int t = 0; t < 4; ++t) acc[t] = (f32x4){0.f, 0.f, 0.f, 0.f};
    #pragma unroll
    for (int kc = 0; kc < 4; ++kc) {
      #pragma unroll
      for (int t = 0; t < 4; ++t) {
        f16x8 a = *(const f16x8*)(fb + ((t * 4 + kc) << 9) + (lane << 3));
        acc[t] = __builtin_amdgcn_mfma_f32_16x16x32_f16(a, bx[kc], acc[t], 0, 0, 0);
      }
    }
    // per-tile top-2 of 4 via min/max network, idx embedded in low bits
    float m1t[4], m2t[4];
    #pragma unroll
    for (int t = 0; t < 4; ++t) {
      const int tj = half * 4 + t;               // tile-in-group
      const int cb = (cs * 64 + hg * 4 + t) * 16 + 4 * q;
      float4 wnq = *(const float4*)(wnorm + cb);
      unsigned b0 = __float_as_uint(fmaf(-2.0f, acc[t][0], wnq.x)) & 0xFFFFFF80u;
      unsigned b1 = __float_as_uint(fmaf(-2.0f, acc[t][1], wnq.y)) & 0xFFFFFF80u;
      unsigned b2 = __float_as_uint(fmaf(-2.0f, acc[t][2], wnq.z)) & 0xFFFFFF80u;
      unsigned b3 = __float_as_uint(fmaf(-2.0f, acc[t][3], wnq.w)) & 0xFFFFFF80u;
      float v0 = __uint_as_float(b0);
      float v1 = __uint_as_float(b1 | 1u);
      float v2 = __uint_as_float(b2 | 2u);
      float v3 = __uint_as_float(b3 | 3u);
      float l1 = fminf(v0, v1), h1 = fmaxf(v0, v1);
      float l2 = fminf(v2, v3), h2 = fmaxf(v2, v3);
      float mm1 = fminf(l1, l2);
      float mm2 = fminf(fminf(h1, h2), fmaxf(l1, l2));
      m1t[t] = __uint_as_float(__float_as_uint(mm1) | (unsigned)(tj << 2));
      m2t[t] = mm2;
    }
    // tournament 4 -> 1 (pure min/max; idx bits ride along)
    m2t[0] = fminf(fminf(m2t[0], m2t[1]), fmaxf(m1t[0], m1t[1]));
    m1t[0] = fminf(m1t[0], m1t[1]);
    m2t[2] = fminf(fminf(m2t[2], m2t[3]), fmaxf(m1t[2], m1t[3]));
    m1t[2] = fminf(m1t[2], m1t[3]);
    m2t[0] = fminf(fminf(m2t[0], m2t[2]), fmaxf(m1t[0], m1t[2]));
    m1t[0] = fminf(m1t[0], m1t[2]);
    if (half == 0) {                             // first half: set carry
      c1 = m1t[0]; c2 = m2t[0];
    } else {                                     // second half: merge + emit
      c2 = fminf(fminf(c2, m2t[0]), fmaxf(c1, m1t[0]));
      c1 = fminf(c1, m1t[0]);
      float d1 = __uint_as_float(__float_as_uint(c1) | q5);
      float d2 = c2;
      // reduce across q (lanes differing in bits 4,5)
      #pragma unroll
      for (int s = 16; s <= 32; s <<= 1) {
        float o1 = __shfl_xor(d1, s), o2 = __shfl_xor(d2, s);
        d2 = fminf(fminf(d2, o2), fmaxf(d1, o1));
        d1 = fminf(d1, o1);
      }
      if (q == 0) {
        const int g = cs * 8 + (hg >> 1);        // group index [0,64)
        size_t pi = (size_t)g * N_ROWS + row;
        pd1[pi] = d1;                            // raw, idx-embedded
        pd2[pi] = d2;                            // raw value
      }
    }
  }
#undef STAGE
}

// ---------------- classify: threshold-collect over 64 groups ---------------
// 4 lanes/row (16 groups each, pd1 kept in registers), shfl merge for the
// global d1 and full/nc flags.  Decodes candidate codes from pd1's embedded
// mantissa bits (q@[6:5] tj@[4:2] r@[1:0]).  wm = exact max||w||^2 reduced
// from wnmax128.  Also inits keys[] + cnt[].
__global__ __launch_bounds__(256) void classify(
    const float* __restrict__ pd1, const float* __restrict__ pd2,
    const float* __restrict__ xnorm, const float* __restrict__ wnmax128,
    int* __restrict__ ids, unsigned* __restrict__ items,
    unsigned* __restrict__ icount, int* __restrict__ fulll,
    unsigned* __restrict__ fcount, unsigned long long* __restrict__ keys,
    unsigned* __restrict__ cnt)
{
  __shared__ float wred[4];
  const int tid = threadIdx.x;
  const int gidx = blockIdx.x * 256 + tid;
  const int row = gidx >> 2, p = gidx & 3;       // 4 lanes per row (same wave)
  if (p == 0) keys[row] = ~0ull;                 // init for refine/resolve
  if (gidx < K_CODES) cnt[gidx] = 0u;
  // exact wm: block-reduce the 128 per-prep-block maxima
  float wv = wnmax128[tid & 127];
  #pragma unroll
  for (int st = 1; st <= 32; st <<= 1) wv = fmaxf(wv, __shfl_xor(wv, st));
  if ((tid & 63) == 0) wred[tid >> 6] = wv;
  __syncthreads();
  const float wm = fmaxf(fmaxf(wred[0], wred[1]), fmaxf(wred[2], wred[3]));

  float v1[16];
  float lmin = __builtin_inff();
  #pragma unroll
  for (int j = 0; j < 16; ++j) {                 // this lane's 16 group-top1s
    v1[j] = pd1[(size_t)(p * 16 + j) * N_ROWS + row];
    lmin = fminf(lmin, v1[j]);
  }
  lmin = fminf(lmin, __shfl_xor(lmin, 1));       // global d1 across 4 lanes
  lmin = fminf(lmin, __shfl_xor(lmin, 2));
  // eps 5e-4 covers 2x 127ulp(|dd|<=8) mantissa-mask error
  float twoE = 2.0f * (0.0029297f * sqrtf(xnorm[row] * wm) + 5e-4f);
  float T = lmin + twoE;
  bool full = false;
  int nc = 0;
  unsigned cands[6];
  #pragma unroll
  for (int j = 0; j < 16; ++j) {
    size_t i = (size_t)(p * 16 + j) * N_ROWS + row;
    if (pd2[i] <= T) { full = true; }
    else if (v1[j] <= T) {
      if (nc < 6) {
        unsigned ui = __float_as_uint(v1[j]) & 127u;
        unsigned g = (unsigned)(p * 16 + j);
        cands[nc++] = (g << 7) | (((ui >> 2) & 7u) << 4) |
                      ((ui >> 5) << 2) | (ui & 3u);
      } else full = true;
    }
  }
  unsigned fm = full ? 1u : 0u;
  int nct = nc;
  fm |= (unsigned)__shfl_xor((int)fm, 1); nct += __shfl_xor(nct, 1);
  fm |= (unsigned)__shfl_xor((int)fm, 2); nct += __shfl_xor(nct, 2);
  if (nct > 6) fm = 1u;                          // cap (conservative-exact)
  if (fm) {
    if (p == 0) { unsigned fi = atomicAdd(fcount, 1u); fulll[fi] = row; }
  } else if (nct >= 2) {
    if (nc > 0) {
      unsigned base = atomicAdd(icount, (unsigned)nc);
      for (int i2 = 0; i2 < nc; ++i2)
        items[base + i2] = ((unsigned)row << 13) | cands[i2];
    }
  } else if (nc == 1) {                          // nct==1, this lane owns it:
    ids[row] = (int)cands[0];                    // unique group within T ->
  }                                              // its top-1 is exact
}

// ---------------- fused exact refine: items (phase A) + full (phase B) -----
// x rows come from xT (row-contiguous fp32) + xnorm.  Safe: each row is
// exclusively phase-A or phase-B; xn is a per-row additive constant.
// Phase B: 8-row batches x 8 codebook slices.  w-slice (512 KB) streamed
// once per 8 rows (was once per row) -> codebook L2 traffic /8.  Each
// (row,code) dot remains ONE thread's c4-major fmaf chain (same order as
// before -> bit-identical keys).
__global__ __launch_bounds__(256) void refine(
    const float* __restrict__ xT, const float* __restrict__ w,
    const float* __restrict__ xnorm, const float* __restrict__ wnorm,
    const unsigned* __restrict__ items, const unsigned* __restrict__ icount,
    const int* __restrict__ fulll, const unsigned* __restrict__ fcount,
    unsigned long long* __restrict__ keys) {
  const int tid = threadIdx.x;
  const int lane = tid & 63, wave = tid >> 6;
  // ---- phase A: candidate items
  const unsigned ic = *icount;
  for (unsigned i = blockIdx.x * 256 + tid; i < ic; i += gridDim.x * 256) {
    unsigned it = items[i];
    int row = (int)(it >> 13), c = (int)(it & 8191u);
    const float* xb = xT + (size_t)row * C_DIM;
    const float* wk = w + (size_t)c * C_DIM;
    float s = 0.f;
    #pragma unroll 8
    for (int c4 = 0; c4 < 32; ++c4) {
      float4 xv = *(const float4*)(xb + c4 * 4);
      float4 wv = *(const float4*)(wk + c4 * 4);
      s = fmaf(xv.x, wv.x, s);
      s = fmaf(xv.y, wv.y, s);
      s = fmaf(xv.z, wv.z, s);
      s = fmaf(xv.w, wv.w, s);
    }
    float d = (xnorm[row] + wnorm[c]) - 2.0f * s;
    unsigned sb = __float_as_uint(d);
    sb = (sb >> 31) ? ~sb : (sb | 0x80000000u);  // sortable float bits
    unsigned long long key = ((unsigned long long)sb << 32) | (unsigned)c;
    atomicMin(&keys[row], key);                  // tie -> lowest code
  }
  // ---- phase B: full rescans, 8-row batches x 8 codebook slices
  __shared__ __align__(16) float xs[8][128];
  __shared__ unsigned long long red[4][8];
  const unsigned fc = *fcount;
  const unsigned nitems = ((fc + 7) >> 3) * 8;
  for (unsigned item = blockIdx.x; item < nitems; item += gridDim.x) {
    const unsigned batch = item >> 3;
    const int slice = (int)(item & 7u);
    int rows[8];
    #pragma unroll
    for (int r = 0; r < 8; ++r) {                // tail: duplicate last row
      unsigned idx = batch * 8 + (unsigned)r;    //  (atomicMin idempotent)
      rows[r] = fulll[idx < fc ? idx : fc - 1];
    }
    #pragma unroll
    for (int rr = 0; rr < 4; ++rr) {             // stage 8 x-rows, coalesced
      int li = rr * 256 + tid;                   // [0,1024)
      xs[li >> 7][li & 127] = xT[(size_t)rows[li >> 7] * C_DIM + (li & 127)];
    }
    __syncthreads();
    float xnr[8];
    #pragma unroll
    for (int r = 0; r < 8; ++r) xnr[r] = xnorm[rows[r]];
    const int k0 = slice * 1024 + tid * 4;
    float S[4][8];
    #pragma unroll
    for (int j = 0; j < 4; ++j)
      #pragma unroll
      for (int r = 0; r < 8; ++r) S[j][r] = 0.f;
    for (int c4 = 0; c4 < 32; ++c4) {
      float4 xv0 = *(const float4*)(&xs[0][c4 * 4]);
      float4 xv1 = *(const float4*)(&xs[1][c4 * 4]);
      float4 xv2 = *(const float4*)(&xs[2][c4 * 4]);
      float4 xv3 = *(const float4*)(&xs[3][c4 * 4]);
      float4 xv4 = *(const float4*)(&xs[4][c4 * 4]);
      float4 xv5 = *(const float4*)(&xs[5][c4 * 4]);
      float4 xv6 = *(const float4*)(&xs[6][c4 * 4]);
      float4 xv7 = *(const float4*)(&xs[7][c4 * 4]);
      #pragma unroll
      for (int j = 0; j < 4; ++j) {
        float4 wv = *(const float4*)(w + (size_t)(k0 + j) * C_DIM + c4 * 4);
        // same xyzw fmaf order per (row,code) as phase A / old phase B
        S[j][0] = fmaf(xv0.x, wv.x, S[j][0]); S[j][0] = fmaf(xv0.y, wv.y, S[j][0]);
        S[j][0] = fmaf(xv0.z, wv.z, S[j][0]); S[j][0] = fmaf(xv0.w, wv.w, S[j][0]);
        S[j][1] = fmaf(xv1.x, wv.x, S[j][1]); S[j][1] = fmaf(xv1.y, wv.y, S[j][1]);
        S[j][1] = fmaf(xv1.z, wv.z, S[j][1]); S[j][1] = fmaf(xv1.w, wv.w, S[j][1]);
        S[j][2] = fmaf(xv2.x, wv.x, S[j][2]); S[j][2] = fmaf(xv2.y, wv.y, S[j][2]);
        S[j][2] = fmaf(xv2.z, wv.z, S[j][2]); S[j][2] = fmaf(xv2.w, wv.w, S[j][2]);
        S[j][3] = fmaf(xv3.x, wv.x, S[j][3]); S[j][3] = fmaf(xv3.y, wv.y, S[j][3]);
        S[j][3] = fmaf(xv3.z, wv.z, S[j][3]); S[j][3] = fmaf(xv3.w, wv.w, S[j][3]);
        S[j][4] = fmaf(xv4.x, wv.x, S[j][4]); S[j][4] = fmaf(xv4.y, wv.y, S[j][4]);
        S[j][4] = fmaf(xv4.z, wv.z, S[j][4]); S[j][4] = fmaf(xv4.w, wv.w, S[j][4]);
        S[j][5] = fmaf(xv5.x, wv.x, S[j][5]); S[j][5] = fmaf(xv5.y, wv.y, S[j][5]);
        S[j][5] = fmaf(xv5.z, wv.z, S[j][5]); S[j][5] = fmaf(xv5.w, wv.w, S[j][5]);
        S[j][6] = fmaf(xv6.x, wv.x, S[j][6]); S[j][6] = fmaf(xv6.y, wv.y, S[j][6]);
        S[j][6] = fmaf(xv6.z, wv.z, S[j][6]); S[j][6] = fmaf(xv6.w, wv.w, S[j][6]);
        S[j][7] = fmaf(xv7.x, wv.x, S[j][7]); S[j][7] = fmaf(xv7.y, wv.y, S[j][7]);
        S[j][7] = fmaf(xv7.z, wv.z, S[j][7]); S[j][7] = fmaf(xv7.w, wv.w, S[j][7]);
      }
    }
    #pragma unroll
    for (int r = 0; r < 8; ++r) {
      unsigned long long best = ~0ull;
      #pragma unroll
      for (int j = 0; j < 4; ++j) {
        float d = (xnr[r] + wnorm[k0 + j]) - 2.0f * S[j][r];
        unsigned sb = __float_as_uint(d);
        sb = (sb >> 31) ? ~sb : (sb | 0x80000000u);
        unsigned long long key =
            ((unsigned long long)sb << 32) | (unsigned)(k0 + j);
        best = best < key ? best : key;
      }
      #pragma unroll
      for (int s = 1; s <= 32; s <<= 1) {        // 64-lane u64 butterfly
        unsigned long long ok = __shfl_xor(best, s);
        best = ok < best ? ok : best;
      }
      if (lane == 0) red[wave][r] = best;
    }
    __syncthreads();
    if (tid < 8) {
      unsigned long long bk = red[0][tid];
      #pragma unroll
      for (int wv = 1; wv < 4; ++wv)
        bk = red[wv][tid] < bk ? red[wv][tid] : bk;
      atomicMin(&keys[rows[tid]], bk);
    }
    __syncthreads();                             // xs/red reused next item
  }
}

// ---------------- resolve final ids + int counts + out_ids -----------------
__global__ void resolve_ids(const unsigned long long* __restrict__ keys,
                            int* __restrict__ ids, unsigned* __restrict__ cnt,
                            float* __restrict__ out_ids) {
  int row = blockIdx.x * 256 + threadIdx.x;
  unsigned long long k = keys[row];
  int id = (k != ~0ull) ? (int)(unsigned)(k & 0xffffffffu) : ids[row];
  ids[row] = id;
  out_ids[row] = (float)id;
  atomicAdd(&cnt[id], 1u);
}

// ---------------- exclusive scan of counts -> offs + cursor (1 block) ------
__global__ __launch_bounds__(256) void scan_offsets(
    const unsigned* __restrict__ cnt,
    unsigned* __restrict__ offs, unsigned* __restrict__ cursor) {
  __shared__ unsigned tot[256];
  const int tid = threadIdx.x;
  unsigned local[32], run = 0;
  #pragma unroll
  for (int i = 0; i < 32; ++i) { local[i] = run; run += cnt[tid * 32 + i]; }
  tot[tid] = run;
  __syncthreads();
  for (int st = 1; st < 256; st <<= 1) {
    unsigned v = (tid >= st) ? tot[tid - st] : 0u;
    __syncthreads();
    tot[tid] += v;
    __syncthreads();
  }
  unsigned excl = (tid == 0) ? 0u : tot[tid - 1];
  #pragma unroll
  for (int i = 0; i < 32; ++i) {
    unsigned o = excl + local[i];
    offs[tid * 32 + i] = o;
    cursor[tid * 32 + i] = o;
  }
}

// ---------------- fill CSR row list (parallel, 64 blocks) ------------------
__global__ void fill_rowlist(const int* __restrict__ ids,
                             unsigned* __restrict__ cursor,
                             int* __restrict__ rowlist) {
  int row = blockIdx.x * 256 + threadIdx.x;
  unsigned slot = atomicAdd(&cursor[ids[row]], 1u);
  rowlist[slot] = row;
}

// ---------------- fused tail: q float4 (blocks<2048) + EMA gather (rest) ---
__global__ __launch_bounds__(256) void qsum_final(
    const float* __restrict__ enc, const float* __restrict__ w,
    const int* __restrict__ ids,
    const unsigned* __restrict__ cnt, const unsigned* __restrict__ offs,
    const int* __restrict__ rowlist, const float* __restrict__ xT,
    float* __restrict__ outq, float* __restrict__ outw) {
  if (blockIdx.x < 2048) {                       // ---- straight-through q
    int e = blockIdx.x * 1024 + threadIdx.x * 4; // linear over enc [B,C,H,W]
    int c = (e >> 10) & 127;
    int b = e >> 17;
    int n = (b << 10) | (e & 1023);              // e..e+3: same b,c
    float4 x = *(const float4*)(enc + e);
    float4 o;
    o.x = x.x + (w[(size_t)ids[n + 0] * C_DIM + c] - x.x);
    o.y = x.y + (w[(size_t)ids[n + 1] * C_DIM + c] - x.y);
    o.z = x.z + (w[(size_t)ids[n + 2] * C_DIM + c] - x.z);
    o.w = x.w + (w[(size_t)ids[n + 3] * C_DIM + c] - x.w);
    *(float4*)(outq + e) = o;
  } else {                                       // ---- EMA gather, wave/code
    const int tid = threadIdx.x;
    const int lane = tid & 63, wave = tid >> 6;
    const int k = (int)(blockIdx.x - 2048) * 4 + wave;
    const unsigned n0 = offs[k], nk = cnt[k];
    float S0a = 0.f, S0b = 0.f, S0c = 0.f, S0d = 0.f;
    float S1a = 0.f, S1b = 0.f, S1c = 0.f, S1d = 0.f;
    unsigned i = 0;
    for (; i + 4 <= nk; i += 4) {                // 4-way ILP partial sums
      int r0 = rowlist[n0 + i],     r1 = rowlist[n0 + i + 1];
      int r2 = rowlist[n0 + i + 2], r3 = rowlist[n0 + i + 3];
      S0a += xT[(size_t)r0 * 128 + lane];      S1a += xT[(size_t)r0 * 128 + lane + 64];
      S0b += xT[(size_t)r1 * 128 + lane];      S1b += xT[(size_t)r1 * 128 + lane + 64];
      S0c += xT[(size_t)r2 * 128 + lane];      S1c += xT[(size_t)r2 * 128 + lane + 64];
      S0d += xT[(size_t)r3 * 128 + lane];      S1d += xT[(size_t)r3 * 128 + lane + 64];
    }
    for (; i < nk; ++i) {
      int r = rowlist[n0 + i];
      S0a += xT[(size_t)r * 128 + lane];
      S1a += xT[(size_t)r * 128 + lane + 64];
    }
    float S0 = (S0a + S0b) + (S0c + S0d);
    float S1 = (S1a + S1b) + (S1c + S1d);
    const float omd = (float)(1.0 - 0.99);
    float cf = (float)nk + 1e-12f;
    outw[(size_t)k * 128 + lane]      = 0.99f * w[(size_t)k * 128 + lane]      + omd * (S0 / cf);
    outw[(size_t)k * 128 + lane + 64] = 0.99f * w[(size_t)k * 128 + lane + 64] + omd * (S1 / cf);
  }
}

// ---------------------------------------------------------------------------
extern "C" void kernel_launch(void* const* d_in, const int* in_sizes, int n_in,
                              void* d_out, int out_size, void* d_ws, size_t ws_size,
                              hipStream_t stream) {
  const float* enc = (const float*)d_in[0];      // [16,128,32,32]
  const float* w   = (const float*)d_in[1];      // [8192,128]
  float* out = (float*)d_out;
  float* out_ids = out;                          // 16384 (ids as float)
  float* out_q   = out + N_ROWS;                 // 2097152
  float* out_w   = out + N_ROWS + N_ROWS * C_DIM;// 1048576

  char* ws = (char*)d_ws;
  _Float16* Ap  = (_Float16*)(ws);                         //  0 .. 4194304
  _Float16* Bp  = (_Float16*)(ws + 4194304);               //  .. 6291456
  float* xnorm  = (float*)(ws + 6291456);                  //  .. 6356992
  float* wnorm  = (float*)(ws + 6356992);                  //  .. 6389760
  float* pd1    = (float*)(ws + 6389760);                  // 4 MB
  float* pd2    = (float*)(ws + 10584064);                 // 4 MB
  float* wnmax128 = (float*)(ws + 14778368);               // 512 B
  int* ids      = (int*)(ws + 18972672);                   // 64 KB
  int* fulll    = (int*)(ws + 19038208);                   // 64 KB
  unsigned* items = (unsigned*)(ws + 19103744);            // 1 MB
  unsigned* icount = (unsigned*)(ws + 20152324);           // ctrl
  unsigned* fcount = (unsigned*)(ws + 20152328);
  unsigned* cnt    = (unsigned*)(ws + 20152336);           // 32 KB (int counts)
  unsigned* offs   = (unsigned*)(ws + 20185104);           // 32 KB
  unsigned* cursor = (unsigned*)(ws + 20217872);           // 32 KB
  unsigned long long* keys = (unsigned long long*)(ws + 20250640); // 128 KB
  int* rowlist  = (int*)(ws + 20381712);                   // 64 KB
  float* xT     = (float*)(ws + 20447248);                 // 8 MB .. 28835856
  (void)in_sizes; (void)n_in; (void)out_size; (void)ws_size;

  // no memset node: icount/fcount zeroed in gemm; keys+cnt init in classify;
  // wnmax128 plain-stored by prep (no init needed)

  prep<<<384, 256, 0, stream>>>(enc, w, Ap, Bp, xT, xnorm, wnorm, wnmax128);
  gemm_argmin<<<dim3(8, N_ROWS / 128), 512, 0, stream>>>(
      Ap, Bp, wnorm, pd1, pd2, icount, fcount);
  classify<<<N_ROWS * 4 / 256, 256, 0, stream>>>(
      pd1, pd2, xnorm, wnmax128, ids, items, icount, fulll, fcount, keys, cnt);
  refine<<<2048, 256, 0, stream>>>(xT, w, xnorm, wnorm, items, icount, fulll,
                                   fcount, keys);
  resolve_ids<<<N_ROWS / 256, 256, 0, stream>>>(keys, ids, cnt, out_ids);
  scan_offsets<<<1, 256, 0, stream>>>(cnt, offs, cursor);
  fill_rowlist<<<N_ROWS / 256, 256, 0, stream>>>(ids, cursor, rowlist);
  qsum_final<<<2048 + K_CODES / 4, 256, 0, stream>>>(
      enc, w, ids, cnt, offs, rowlist, xT, out_q, out_w);
}

// Round 11
// 187.932 us; speedup vs baseline: 1.1228x; 1.0598x over previous
//
#include <hip/hip_runtime.h>
#include <stdint.h>
#include <stddef.h>

// ---------------------------------------------------------------------------
// VQ-VAE quantizer, MI355X.  dist(n,k) = ||x||^2 + ||w_k||^2 - 2 x.w_k.
// f16 GEMM (KD=128), fragment-linear A/B.
// Refine: per-row threshold T = d1~ + 2E; exact compares via u64 atomicMin.
// R16: fragments staged via global_load_lds (2x16 KB dbuf, 4 blk/CU).
// R21: refine item batching.  R9/R20 ablations: gemm flat 55 us across
// occupancy 31-56% and LDS-read halving -> VALU-issue floor; stop tuning.
// R22 (this round): HALF-GROUP refine granularity.  gemm emits per-64-code
// half (d1,d2), 6-bit in-half idx embedded in BOTH (mask 0xFFFFFFC0,
// |(t<<4)|r at convert, |q<<2 pre-shfl; idx bits ride min/max); carry
// merge removed; pd2 stored round-DOWN bf16 (conservative).  classify:
// half pd2<=T -> (row,half) 64-code rescan item; pd1<=T -> candidate
// h*64+(bits&63); cap-overflow degrades to half-rescans (exact).  refine
// phase B: block per (row,half), 256thr x 64 codes x 4 dim-quarters,
// coalesced w; FULL-codebook rescan eliminated (was fcount x 2 MFLOP ~
// 25-50 us of VALU).  Mask err <=63ulp + bf16-down 0.004 inside 5e-4 eps.
// ---------------------------------------------------------------------------

#define N_ROWS   16384      // B*H*W = 16*32*32
#define K_CODES  8192
#define C_DIM    128
#define ITEMS_CAP 32768u

typedef _Float16 f16x8 __attribute__((ext_vector_type(8)));
typedef float    f32x4 __attribute__((ext_vector_type(4)));

// ---------------- fused prep: blocks [0,256) pack x (+fp32 xT), [256,384) w
__global__ __launch_bounds__(256) void prep(const float* __restrict__ enc,
                                            const float* __restrict__ w,
                                            _Float16* __restrict__ Ap,
                                            _Float16* __restrict__ Bp,
                                            float* __restrict__ xT,
                                            float* __restrict__ xnorm,
                                            float* __restrict__ wnorm,
                                            float* __restrict__ wnmax128) {
  __shared__ float t[128][65];
  const int tid = threadIdx.x;
  if (blockIdx.x < 256) {                        // ---- x path
    const int b = blockIdx.x >> 4;
    const int hw0 = (blockIdx.x & 15) << 6;
    #pragma unroll
    for (int i = 0; i < 32; ++i) {
      int idx = i * 256 + tid;
      int c = idx >> 6, hwl = idx & 63;
      t[c][hwl] = enc[((size_t)(b * 128 + c) << 10) + hw0 + hwl];
    }
    __syncthreads();
    const int r = tid >> 2, sub = tid & 3;       // row-in-block, k-chunk
    const int n = (b << 10) + hw0 + r;
    const int R = n >> 4, m = n & 15;
    float s = 0.f;
    #pragma unroll
    for (int q = 0; q < 4; ++q) {
      f16x8 hv;
      float vv[8];
      #pragma unroll
      for (int e = 0; e < 8; ++e) {
        float v = t[sub * 32 + q * 8 + e][r];
        vv[e] = v;
        s += v * v;
        hv[e] = (_Float16)v;
      }
      *(f16x8*)(Ap + ((size_t)(R * 4 + sub) * 64 + (m + 16 * q)) * 8) = hv;
      *(float4*)(xT + (size_t)n * 128 + sub * 32 + q * 8) =
          (float4){vv[0], vv[1], vv[2], vv[3]};
      *(float4*)(xT + (size_t)n * 128 + sub * 32 + q * 8 + 4) =
          (float4){vv[4], vv[5], vv[6], vv[7]};
    }
    s += __shfl_xor(s, 1);
    s += __shfl_xor(s, 2);
    if (sub == 0) xnorm[n] = s;
  } else {                                       // ---- w path
    __shared__ float wred[4];
    const int kk = (blockIdx.x - 256) * 64 + (tid >> 2), sub = tid & 3;
    const int R = kk >> 4, m = kk & 15;
    const float* base = w + (size_t)kk * C_DIM + sub * 32;
    float s = 0.f;
    #pragma unroll
    for (int q = 0; q < 4; ++q) {
      f16x8 hv;
      float4 va = *(const float4*)(base + q * 8);
      float4 vb = *(const float4*)(base + q * 8 + 4);
      float vv[8] = {va.x, va.y, va.z, va.w, vb.x, vb.y, vb.z, vb.w};
      #pragma unroll
      for (int e = 0; e < 8; ++e) { s += vv[e] * vv[e]; hv[e] = (_Float16)vv[e]; }
      *(f16x8*)(Bp + ((size_t)(R * 4 + sub) * 64 + (m + 16 * q)) * 8) = hv;
    }
    s += __shfl_xor(s, 1);                       // all 4 quad lanes: norm(kk)
    s += __shfl_xor(s, 2);
    if (sub == 0) wnorm[kk] = s;
    float wx = s;                                // block max of 64 norms
    #pragma unroll
    for (int st = 1; st <= 32; st <<= 1) wx = fmaxf(wx, __shfl_xor(wx, st));
    if ((tid & 63) == 0) wred[tid >> 6] = wx;
    __syncthreads();
    if (tid == 0)
      wnmax128[blockIdx.x - 256] =
          fmaxf(fmaxf(wred[0], wred[1]), fmaxf(wred[2], wred[3]));
  }
}

// ---------------- main GEMM + per-(row,64col-half) top-2 -------------------
// Grid (8 colsplits, 128 rowblocks), 512 thr = 8 waves.  Wave: 16 rows x
// 64 codes per half-group (4 tiles, 16 KB staged dbuf).  mfma(a=codes,
// b=rows): D col = lane&15 = x-row, D row = 4q+r = code.  6-bit in-half
// idx (t@[5:4], q@[3:2], r@[1:0]) embedded in the low mantissa of BOTH
// d1 and d2 (rides min/max); per-half emit: pd1h f32, pd2h bf16 rounded
// DOWN (conservative).  code = h*64 + (bits&63).
__global__ __launch_bounds__(512) void gemm_argmin(
    const _Float16* __restrict__ Ap, const _Float16* __restrict__ Bp,
    const float* __restrict__ wnorm,
    float* __restrict__ pd1h, unsigned short* __restrict__ pd2h,
    unsigned* __restrict__ icount, unsigned* __restrict__ hcount)
{
  __shared__ _Float16 sbuf[2][8192];             // 2 x 16 KB half-group bufs
  const int tid = threadIdx.x;
  const int lane = tid & 63, wave = tid >> 6;    // 8 waves
  const int m = lane & 15, q = lane >> 4;
  const int cs = blockIdx.x;                     // col slice (1024 codes)
  const int row0 = blockIdx.y * 128;
  const int Tr = blockIdx.y * 8 + wave;          // wave's 16-row tile

  if (cs == 0 && blockIdx.y == 0 && tid == 0) {  // ctrl zero (pre-classify)
    *icount = 0u; *hcount = 0u;
  }

#define STAGE(b, hgn) do {                                                   \
    const size_t bh_ = ((size_t)((cs * 64 + (hgn) * 4) * 4) << 9);           \
    _Pragma("unroll")                                                        \
    for (int r_ = 0; r_ < 2; ++r_) {                                         \
      __builtin_amdgcn_global_load_lds(                                      \
          (const __attribute__((address_space(1))) void*)                    \
              (Bp + bh_ + ((size_t)(r_ * 512 + tid) << 3)),                  \
          (__attribute__((address_space(3))) void*)                          \
              (&sbuf[b][(r_ * 512 + tid) << 3]),                             \
          16, 0, 0);                                                         \
    }                                                                        \
  } while (0)

  f16x8 bx[4];                                   // x-row fragments (invariant)
  #pragma unroll
  for (int kc = 0; kc < 4; ++kc)
    bx[kc] = *(const f16x8*)(Ap + (((size_t)Tr * 4 + kc) << 9) + (lane << 3));
  const int row = row0 + wave * 16 + m;
  const unsigned q2 = (unsigned)(q << 2);

  STAGE(0, 0);                                   // prologue stage

  for (int hg = 0; hg < 16; ++hg) {              // ascending half-groups
    __syncthreads();                             // buf[hg&1] ready
    if (hg < 15) STAGE((hg + 1) & 1, hg + 1);    // prefetch next half
    const _Float16* fb = &sbuf[hg & 1][0];
    f32x4 acc[4];
    #pragma unroll
    for (int t = 0; t < 4; ++t) acc[t] = (f32x4){0.f, 0.f, 0.f, 0.f};
    #pragma unroll
    for (int kc = 0; kc < 4; ++kc) {
      #pragma unroll
      for (int t = 0; t < 4; ++t) {
        f16x8 a = *(const f16x8*)(fb + ((t * 4 + kc) << 9) + (lane << 3));
        acc[t] = __builtin_amdgcn_mfma_f32_16x16x32_f16(a, bx[kc], acc[t], 0, 0, 0);
      }
    }
    // per-tile top-2 of 4 via min/max; 6-bit idx embedded pre-network
    float m1t[4], m2t[4];
    #pragma unroll
    for (int t = 0; t < 4; ++t) {
      const int cb = (cs * 64 + hg * 4 + t) * 16 + 4 * q;
      float4 wnq = *(const float4*)(wnorm + cb);
      const unsigned e0 = (unsigned)(t << 4);
      unsigned b0 = (__float_as_uint(fmaf(-2.0f, acc[t][0], wnq.x)) & 0xFFFFFFC0u) | e0;
      unsigned b1 = (__float_as_uint(fmaf(-2.0f, acc[t][1], wnq.y)) & 0xFFFFFFC0u) | (e0 | 1u);
      unsigned b2 = (__float_as_uint(fmaf(-2.0f, acc[t][2], wnq.z)) & 0xFFFFFFC0u) | (e0 | 2u);
      unsigned b3 = (__float_as_uint(fmaf(-2.0f, acc[t][3], wnq.w)) & 0xFFFFFFC0u) | (e0 | 3u);
      float v0 = __uint_as_float(b0);
      float v1 = __uint_as_float(b1);
      float v2 = __uint_as_float(b2);
      float v3 = __uint_as_float(b3);
      float l1 = fminf(v0, v1), h1 = fmaxf(v0, v1);
      float l2 = fminf(v2, v3), h2 = fmaxf(v2, v3);
      m1t[t] = fminf(l1, l2);
      m2t[t] = fminf(fminf(h1, h2), fmaxf(l1, l2));
    }
    // tournament 4 -> 1 (idx bits ride along)
    m2t[0] = fminf(fminf(m2t[0], m2t[1]), fmaxf(m1t[0], m1t[1]));
    m1t[0] = fminf(m1t[0], m1t[1]);
    m2t[2] = fminf(fminf(m2t[2], m2t[3]), fmaxf(m1t[2], m1t[3]));
    m1t[2] = fminf(m1t[2], m1t[3]);
    m2t[0] = fminf(fminf(m2t[0], m2t[2]), fmaxf(m1t[0], m1t[2]));
    m1t[0] = fminf(m1t[0], m1t[2]);
    float d1 = __uint_as_float(__float_as_uint(m1t[0]) | q2);
    float d2 = __uint_as_float(__float_as_uint(m2t[0]) | q2);
    // reduce across q (lanes differing in bits 4,5)
    #pragma unroll
    for (int s = 16; s <= 32; s <<= 1) {
      float o1 = __shfl_xor(d1, s), o2 = __shfl_xor(d2, s);
      d2 = fminf(fminf(d2, o2), fmaxf(d1, o1));
      d1 = fminf(d1, o1);
    }
    if (q == 0) {
      const int h = cs * 16 + hg;                // half index [0,128)
      pd1h[(size_t)h * N_ROWS + row] = d1;       // raw, idx-embedded
      unsigned bb = __float_as_uint(d2);
      bb += ((unsigned)((int)bb >> 31)) & 0xFFFFu;  // round toward -inf
      pd2h[(size_t)h * N_ROWS + row] = (unsigned short)(bb >> 16);
    }
  }
#undef STAGE
}

// ---------------- classify: threshold-collect over 128 halves --------------
// 4 lanes/row x 32 halves.  half pd2<=T -> (row,half) rescan item; else
// pd1<=T -> candidate h*64+(bits&63).  Cap overflows degrade to rescans
// (exactness preserved).  wm = exact max||w||^2.  Inits keys/cnt.
__global__ __launch_bounds__(256) void classify(
    const float* __restrict__ pd1h, const unsigned short* __restrict__ pd2h,
    const float* __restrict__ xnorm, const float* __restrict__ wnmax128,
    int* __restrict__ ids, unsigned* __restrict__ items,
    unsigned* __restrict__ icount, unsigned* __restrict__ hlist,
    unsigned* __restrict__ hcount, unsigned long long* __restrict__ keys,
    unsigned* __restrict__ cnt)
{
  __shared__ float wred[4];
  const int tid = threadIdx.x;
  const int gidx = blockIdx.x * 256 + tid;
  const int row = gidx >> 2, p = gidx & 3;       // 4 lanes per row (same wave)
  if (p == 0) keys[row] = ~0ull;                 // init for refine/resolve
  if (gidx < K_CODES) cnt[gidx] = 0u;
  // exact wm: block-reduce the 128 per-prep-block maxima
  float wv = wnmax128[tid & 127];
  #pragma unroll
  for (int st = 1; st <= 32; st <<= 1) wv = fmaxf(wv, __shfl_xor(wv, st));
  if ((tid & 63) == 0) wred[tid >> 6] = wv;
  __syncthreads();
  const float wm = fmaxf(fmaxf(wred[0], wred[1]), fmaxf(wred[2], wred[3]));

  float v1[32];
  float lmin = __builtin_inff();
  #pragma unroll
  for (int j = 0; j < 32; ++j) {                 // this lane's 32 half-top1s
    v1[j] = pd1h[(size_t)(p * 32 + j) * N_ROWS + row];
    lmin = fminf(lmin, v1[j]);
  }
  lmin = fminf(lmin, __shfl_xor(lmin, 1));       // global d1 across 4 lanes
  lmin = fminf(lmin, __shfl_xor(lmin, 2));
  // eps 5e-4 covers 63ulp idx-mask + conservative bf16 handling
  float twoE = 2.0f * (0.0029297f * sqrtf(xnorm[row] * wm) + 5e-4f);
  float T = lmin + twoE;
  int nc = 0, hr = 0;
  unsigned cands[6];
  #pragma unroll 8
  for (int j = 0; j < 32; ++j) {
    const int h = p * 32 + j;
    float p2 = __uint_as_float(
        (unsigned)pd2h[(size_t)h * N_ROWS + row] << 16);  // <= true pd2
    if (p2 <= T) {                               // 64-code rescan item
      unsigned hi = atomicAdd(hcount, 1u);
      hlist[hi] = ((unsigned)row << 7) | (unsigned)h;
      hr++;
    } else if (v1[j] <= T) {
      if (nc < 6) {
        cands[nc++] = (unsigned)h * 64u + (__float_as_uint(v1[j]) & 63u);
      } else {                                   // cap: degrade to rescan
        unsigned hi = atomicAdd(hcount, 1u);
        hlist[hi] = ((unsigned)row << 7) | (unsigned)h;
        hr++;
      }
    }
  }
  int nct = nc + __shfl_xor(nc, 1); nct += __shfl_xor(nct, 2);
  int hrt = hr + __shfl_xor(hr, 1); hrt += __shfl_xor(hrt, 2);
  if (hrt == 0 && nct == 1) {                    // unique candidate -> exact
    if (nc == 1) ids[row] = (int)cands[0];
  } else if (nc > 0) {                           // push this lane's cands
    unsigned base = atomicAdd(icount, (unsigned)nc);
    if (base + (unsigned)nc <= ITEMS_CAP) {
      for (int i2 = 0; i2 < nc; ++i2)
        items[base + i2] = ((unsigned)row << 13) | cands[i2];
    } else {                                     // overflow: rescan halves
      for (int i2 = 0; i2 < nc; ++i2) {
        unsigned hi = atomicAdd(hcount, 1u);
        hlist[hi] = ((unsigned)row << 7) | (cands[i2] >> 6);
      }
    }
  }
}

// ---------------- fused exact refine: items (phase A) + halves (phase B) ---
// x from xT (row-contiguous fp32) + xnorm; xn is per-row additive constant.
// Phase B: one block per (row,half): 64 codes x 4 dim-quarters, coalesced
// w reads; shfl-combine quarters; wave u64-min -> atomicMin.
__global__ __launch_bounds__(256) void refine(
    const float* __restrict__ xT, const float* __restrict__ w,
    const float* __restrict__ xnorm, const float* __restrict__ wnorm,
    const unsigned* __restrict__ items, const unsigned* __restrict__ icount,
    const unsigned* __restrict__ hlist, const unsigned* __restrict__ hcount,
    unsigned long long* __restrict__ keys) {
  const int tid = threadIdx.x;
  const int lane = tid & 63, wave = tid >> 6;
  // ---- phase A: candidate items
  const unsigned ic = *icount;
  const unsigned ica = ic <= ITEMS_CAP ? ic : ITEMS_CAP;
  for (unsigned i = blockIdx.x * 256 + tid; i < ica; i += gridDim.x * 256) {
    unsigned it = items[i];
    int row = (int)(it >> 13), c = (int)(it & 8191u);
    const float* xb = xT + (size_t)row * C_DIM;
    const float* wk = w + (size_t)c * C_DIM;
    float s = 0.f;
    #pragma unroll 8
    for (int c4 = 0; c4 < 32; ++c4) {
      float4 xv = *(const float4*)(xb + c4 * 4);
      float4 wv = *(const float4*)(wk + c4 * 4);
      s = fmaf(xv.x, wv.x, s);
      s = fmaf(xv.y, wv.y, s);
      s = fmaf(xv.z, wv.z, s);
      s = fmaf(xv.w, wv.w, s);
    }
    float d = (xnorm[row] + wnorm[c]) - 2.0f * s;
    unsigned sb = __float_as_uint(d);
    sb = (sb >> 31) ? ~sb : (sb | 0x80000000u);  // sortable float bits
    unsigned long long key = ((unsigned long long)sb << 32) | (unsigned)c;
    atomicMin(&keys[row], key);                  // tie -> lowest code
  }
  // ---- phase B: 64-code half rescans
  __shared__ __align__(16) float xs[128];
  __shared__ unsigned long long red[4];
  const unsigned hc = *hcount;
  for (unsigned item = blockIdx.x; item < hc; item += gridDim.x) {
    const unsigned e = hlist[item];
    const int row = (int)(e >> 7), h = (int)(e & 127u);
    if (tid < 128)                               // stage x row (coalesced)
      xs[tid] = xT[(size_t)row * C_DIM + tid];
    __syncthreads();
    const int code = h * 64 + (tid >> 2);
    const int qt = tid & 3;
    const float* wk = w + (size_t)code * C_DIM + qt * 32;
    float s = 0.f;
    #pragma unroll
    for (int c4 = 0; c4 < 8; ++c4) {
      float4 wv = *(const float4*)(wk + c4 * 4);
      float4 xv = *(const float4*)(&xs[qt * 32 + c4 * 4]);
      s = fmaf(xv.x, wv.x, s);
      s = fmaf(xv.y, wv.y, s);
      s = fmaf(xv.z, wv.z, s);
      s = fmaf(xv.w, wv.w, s);
    }
    s += __shfl_xor(s, 1);                       // combine 4 dim-quarters
    s += __shfl_xor(s, 2);
    unsigned long long best = ~0ull;
    if (qt == 0) {
      float d = (xnorm[row] + wnorm[code]) - 2.0f * s;
      unsigned sb = __float_as_uint(d);
      sb = (sb >> 31) ? ~sb : (sb | 0x80000000u);
      best = ((unsigned long long)sb << 32) | (unsigned)code;
    }
    #pragma unroll
    for (int st = 1; st <= 32; st <<= 1) {       // 64-lane u64 butterfly
      unsigned long long ok = __shfl_xor(best, st);
      best = ok < best ? ok : best;
    }
    if (lane == 0) red[wave] = best;
    __syncthreads();
    if (tid == 0) {
      unsigned long long bk = red[0];
      #pragma unroll
      for (int wv = 1; wv < 4; ++wv) bk = red[wv] < bk ? red[wv] : bk;
      atomicMin(&keys[row], bk);
    }
    __syncthreads();                             // xs/red reused next item
  }
}

// ---------------- resolve final ids + int counts + out_ids -----------------
__global__ void resolve_ids(const unsigned long long* __restrict__ keys,
                            int* __restrict__ ids, unsigned* __restrict__ cnt,
                            float* __restrict__ out_ids) {
  int row = blockIdx.x * 256 + threadIdx.x;
  unsigned long long k = keys[row];
  int id = (k != ~0ull) ? (int)(unsigned)(k & 0xffffffffu) : ids[row];
  ids[row] = id;
  out_ids[row] = (float)id;
  atomicAdd(&cnt[id], 1u);
}

// ---------------- exclusive scan of counts -> offs + cursor (1 block) ------
__global__ __launch_bounds__(256) void scan_offsets(
    const unsigned* __restrict__ cnt,
    unsigned* __restrict__ offs, unsigned* __restrict__ cursor) {
  __shared__ unsigned tot[256];
  const int tid = threadIdx.x;
  unsigned local[32], run = 0;
  #pragma unroll
  for (int i = 0; i < 32; ++i) { local[i] = run; run += cnt[tid * 32 + i]; }
  tot[tid] = run;
  __syncthreads();
  for (int st = 1; st < 256; st <<= 1) {
    unsigned v = (tid >= st) ? tot[tid - st] : 0u;
    __syncthreads();
    tot[tid] += v;
    __syncthreads();
  }
  unsigned excl = (tid == 0) ? 0u : tot[tid - 1];
  #pragma unroll
  for (int i = 0; i < 32; ++i) {
    unsigned o = excl + local[i];
    offs[tid * 32 + i] = o;
    cursor[tid * 32 + i] = o;
  }
}

// ---------------- fill CSR row list (parallel, 64 blocks) ------------------
__global__ void fill_rowlist(const int* __restrict__ ids,
                             unsigned* __restrict__ cursor,
                             int* __restrict__ rowlist) {
  int row = blockIdx.x * 256 + threadIdx.x;
  unsigned slot = atomicAdd(&cursor[ids[row]], 1u);
  rowlist[slot] = row;
}

// ---------------- fused tail: q float4 (blocks<2048) + EMA gather (rest) ---
__global__ __launch_bounds__(256) void qsum_final(
    const float* __restrict__ enc, const float* __restrict__ w,
    const int* __restrict__ ids,
    const unsigned* __restrict__ cnt, const unsigned* __restrict__ offs,
    const int* __restrict__ rowlist, const float* __restrict__ xT,
    float* __restrict__ outq, float* __restrict__ outw) {
  if (blockIdx.x < 2048) {                       // ---- straight-through q
    int e = blockIdx.x * 1024 + threadIdx.x * 4; // linear over enc [B,C,H,W]
    int c = (e >> 10) & 127;
    int b = e >> 17;
    int n = (b << 10) | (e & 1023);              // e..e+3: same b,c
    float4 x = *(const float4*)(enc + e);
    float4 o;
    o.x = x.x + (w[(size_t)ids[n + 0] * C_DIM + c] - x.x);
    o.y = x.y + (w[(size_t)ids[n + 1] * C_DIM + c] - x.y);
    o.z = x.z + (w[(size_t)ids[n + 2] * C_DIM + c] - x.z);
    o.w = x.w + (w[(size_t)ids[n + 3] * C_DIM + c] - x.w);
    *(float4*)(outq + e) = o;
  } else {                                       // ---- EMA gather, wave/code
    const int tid = threadIdx.x;
    const int lane = tid & 63, wave = tid >> 6;
    const int k = (int)(blockIdx.x - 2048) * 4 + wave;
    const unsigned n0 = offs[k], nk = cnt[k];
    float S0a = 0.f, S0b = 0.f, S0c = 0.f, S0d = 0.f;
    float S1a = 0.f, S1b = 0.f, S1c = 0.f, S1d = 0.f;
    unsigned i = 0;
    for (; i + 4 <= nk; i += 4) {                // 4-way ILP partial sums
      int r0 = rowlist[n0 + i],     r1 = rowlist[n0 + i + 1];
      int r2 = rowlist[n0 + i + 2], r3 = rowlist[n0 + i + 3];
      S0a += xT[(size_t)r0 * 128 + lane];      S1a += xT[(size_t)r0 * 128 + lane + 64];
      S0b += xT[(size_t)r1 * 128 + lane];      S1b += xT[(size_t)r1 * 128 + lane + 64];
      S0c += xT[(size_t)r2 * 128 + lane];      S1c += xT[(size_t)r2 * 128 + lane + 64];
      S0d += xT[(size_t)r3 * 128 + lane];      S1d += xT[(size_t)r3 * 128 + lane + 64];
    }
    for (; i < nk; ++i) {
      int r = rowlist[n0 + i];
      S0a += xT[(size_t)r * 128 + lane];
      S1a += xT[(size_t)r * 128 + lane + 64];
    }
    float S0 = (S0a + S0b) + (S0c + S0d);
    float S1 = (S1a + S1b) + (S1c + S1d);
    const float omd = (float)(1.0 - 0.99);
    float cf = (float)nk + 1e-12f;
    outw[(size_t)k * 128 + lane]      = 0.99f * w[(size_t)k * 128 + lane]      + omd * (S0 / cf);
    outw[(size_t)k * 128 + lane + 64] = 0.99f * w[(size_t)k * 128 + lane + 64] + omd * (S1 / cf);
  }
}

// ---------------------------------------------------------------------------
extern "C" void kernel_launch(void* const* d_in, const int* in_sizes, int n_in,
                              void* d_out, int out_size, void* d_ws, size_t ws_size,
                              hipStream_t stream) {
  const float* enc = (const float*)d_in[0];      // [16,128,32,32]
  const float* w   = (const float*)d_in[1];      // [8192,128]
  float* out = (float*)d_out;
  float* out_ids = out;                          // 16384 (ids as float)
  float* out_q   = out + N_ROWS;                 // 2097152
  float* out_w   = out + N_ROWS + N_ROWS * C_DIM;// 1048576

  char* ws = (char*)d_ws;
  _Float16* Ap  = (_Float16*)(ws);                         //  0 .. 4194304
  _Float16* Bp  = (_Float16*)(ws + 4194304);               //  .. 6291456
  float* xnorm  = (float*)(ws + 6291456);                  //  .. 6356992
  float* wnorm  = (float*)(ws + 6356992);                  //  .. 6389760
  float* pd1h   = (float*)(ws + 6389760);                  // 8 MB [128][16384]
  unsigned short* pd2h = (unsigned short*)(ws + 14778368); // 4 MB bf16
  float* wnmax128 = (float*)(ws + 18972672);               // 512 B
  int* ids      = (int*)(ws + 18973184);                   // 64 KB
  unsigned* hlist = (unsigned*)(ws + 19038720);            // 512 KB
  unsigned* items = (unsigned*)(ws + 19563008);            // 128 KB
  unsigned* icount = (unsigned*)(ws + 19694080);           // ctrl
  unsigned* hcount = (unsigned*)(ws + 19694084);
  unsigned* cnt    = (unsigned*)(ws + 19694096);           // 32 KB
  unsigned* offs   = (unsigned*)(ws + 19726864);           // 32 KB
  unsigned* cursor = (unsigned*)(ws + 19759632);           // 32 KB
  unsigned long long* keys = (unsigned long long*)(ws + 19792400); // 128 KB
  int* rowlist  = (int*)(ws + 19923472);                   // 64 KB
  float* xT     = (float*)(ws + 20447248);                 // 8 MB .. 28835856
  (void)in_sizes; (void)n_in; (void)out_size; (void)ws_size;

  // no memset node: icount/hcount zeroed in gemm; keys+cnt init in classify;
  // wnmax128 plain-stored by prep

  prep<<<384, 256, 0, stream>>>(enc, w, Ap, Bp, xT, xnorm, wnorm, wnmax128);
  gemm_argmin<<<dim3(8, N_ROWS / 128), 512, 0, stream>>>(
      Ap, Bp, wnorm, pd1h, pd2h, icount, hcount);
  classify<<<N_ROWS * 4 / 256, 256, 0, stream>>>(
      pd1h, pd2h, xnorm, wnmax128, ids, items, icount, hlist, hcount,
      keys, cnt);
  refine<<<2048, 256, 0, stream>>>(xT, w, xnorm, wnorm, items, icount,
                                   hlist, hcount, keys);
  resolve_ids<<<N_ROWS / 256, 256, 0, stream>>>(keys, ids, cnt, out_ids);
  scan_offsets<<<1, 256, 0, stream>>>(cnt, offs, cursor);
  fill_rowlist<<<N_ROWS / 256, 256, 0, stream>>>(ids, cursor, rowlist);
  qsum_final<<<2048 + K_CODES / 4, 256, 0, stream>>>(
      enc, w, ids, cnt, offs, rowlist, xT, out_q, out_w);
}